// Round 1
// baseline (18.443 us; speedup 1.0000x reference)
//
#include <hip/hip_runtime.h>

constexpr int NE = 8;       // N_ELEMENT
constexpr int NL = 32;      // N_LINES
constexpr int MB = 512;     // MINIBATCH
constexpr int SN = 1024;    // SAMPLE_N
constexpr float KS   = 0.01f / 1024.0f;  // SAMPLE_CM / SAMPLE_N
constexpr float I0   = 100000.0f;        // PROBE_I0
constexpr float OUTS = 0.05f;            // DET_SOLID_ANGLE_RATIO * SIGNAL_ATT

// One block per batch row b. 256 threads; thread t owns samples 4t..4t+3.
__global__ __launch_bounds__(256)
void ppm_kernel(const float* __restrict__ xp,   // [8][512][1024]
                const float* __restrict__ mu,   // [8]
                const float* __restrict__ fl,   // [32]
                const float* __restrict__ SA,   // [32][512*1024]
                float* __restrict__ out)        // [32*512 fl_signal | 512 trans]
{
    const int b    = blockIdx.x;
    const int t    = threadIdx.x;
    const int lane = t & 63;
    const int wv   = t >> 6;

    __shared__ float s_wave[4];
    __shared__ float s_acc[256 * 33];   // [thread][line], stride 33 kills conflicts
    __shared__ float s_part[256];       // [group(8)][line(32)]

    // ---- load xp fragments: 8 elements x 4 samples (float4, coalesced) ----
    float x[NE][4];
    #pragma unroll
    for (int e = 0; e < NE; ++e) {
        const float4 v = reinterpret_cast<const float4*>(
            xp + (size_t)e * (MB * SN) + (size_t)b * SN)[t];
        x[e][0] = v.x; x[e][1] = v.y; x[e][2] = v.z; x[e][3] = v.w;
    }

    // ---- per-sample attenuation increments A[s] = sum_e mu_e * xp_e[s] ----
    float a0 = 0.f, a1 = 0.f, a2 = 0.f, a3 = 0.f;
    #pragma unroll
    for (int e = 0; e < NE; ++e) {
        const float m = mu[e];
        a0 = fmaf(m, x[e][0], a0);
        a1 = fmaf(m, x[e][1], a1);
        a2 = fmaf(m, x[e][2], a2);
        a3 = fmaf(m, x[e][3], a3);
    }

    // local exclusive prefixes within the 4-sample chunk
    const float e1 = a0, e2 = a0 + a1, e3 = e2 + a2;
    const float T  = e3 + a3;               // chunk total

    // ---- wave-level inclusive scan of chunk totals (width 64) ----
    float incl = T;
    #pragma unroll
    for (int d = 1; d < 64; d <<= 1) {
        const float v = __shfl_up(incl, d, 64);
        if (lane >= d) incl += v;
    }
    if (lane == 63) s_wave[wv] = incl;
    __syncthreads();

    // cross-wave exclusive offset
    float woff = 0.f;
    for (int w2 = 0; w2 < wv; ++w2) woff += s_wave[w2];
    const float bex = woff + (incl - T);    // block-level exclusive prefix

    // transmission_att_exponent[b] = KS * grand total
    if (t == 0) {
        out[NL * MB + b] = KS * (s_wave[0] + s_wave[1] + s_wave[2] + s_wave[3]);
    }

    // ---- attenuation weights, folded into xp fragments ----
    const float w0 = I0 * __expf(-KS * bex);
    const float w1 = I0 * __expf(-KS * (bex + e1));
    const float w2 = I0 * __expf(-KS * (bex + e2));
    const float w3 = I0 * __expf(-KS * (bex + e3));
    #pragma unroll
    for (int e = 0; e < NE; ++e) {
        x[e][0] *= w0; x[e][1] *= w1; x[e][2] *= w2; x[e][3] *= w3;
    }

    // ---- 32 line dot-product partials against SA_theta (float4, coalesced) ----
    const size_t sabase = (size_t)b * SN;
    #pragma unroll 8
    for (int l = 0; l < NL; ++l) {
        const float4 sa = reinterpret_cast<const float4*>(
            SA + (size_t)l * (size_t)(MB * SN) + sabase)[t];
        const int e = l >> 2;
        const float acc = x[e][0] * sa.x + x[e][1] * sa.y
                        + x[e][2] * sa.z + x[e][3] * sa.w;
        s_acc[t * 33 + l] = acc;
    }
    __syncthreads();

    // ---- block reduction: 256 partials per line -> 8 group partials ----
    {
        const int l = t & 31, g = t >> 5;
        float s = 0.f;
        #pragma unroll
        for (int j = 0; j < 32; ++j) s += s_acc[(g * 32 + j) * 33 + l];
        s_part[t] = s;   // t == g*32 + l
    }
    __syncthreads();

    // ---- final: 8 group partials -> fl_signal[l][b] ----
    if (t < 32) {
        float tot = 0.f;
        #pragma unroll
        for (int g2 = 0; g2 < 8; ++g2) tot += s_part[g2 * 32 + t];
        out[t * MB + b] = OUTS * fl[t] * tot;
    }
}

extern "C" void kernel_launch(void* const* d_in, const int* in_sizes, int n_in,
                              void* d_out, int out_size, void* d_ws, size_t ws_size,
                              hipStream_t stream) {
    const float* xp = (const float*)d_in[0];
    const float* mu = (const float*)d_in[1];
    const float* fl = (const float*)d_in[2];
    const float* SA = (const float*)d_in[3];
    float* out = (float*)d_out;
    ppm_kernel<<<MB, 256, 0, stream>>>(xp, mu, fl, SA, out);
}